// Round 13
// baseline (275.203 us; speedup 1.0000x reference)
//
#include <hip/hip_runtime.h>

#define DHID 128
#define BCAP 10240         // per-bucket capacity (mean 8163, 23 sigma)
#define PCHUNK 4096        // edges per partition block
#define XS_LD 136          // LDS row stride in fp16 elems (128 + 8 pad)
#define W2_LD 132          // LDS stride for W2t tile (4-way conflict max)
#define SMEM_PART 21504    // partition smem bytes
#define SMEM_MID  17408    // gemm1 tile 64*136*2 (> p2b's 6144)

typedef _Float16 h4 __attribute__((ext_vector_type(4)));
typedef _Float16 h8 __attribute__((ext_vector_type(8)));
typedef float    f32x4 __attribute__((ext_vector_type(4)));
typedef int      i32x4 __attribute__((ext_vector_type(4)));

// ---- hoist A-frags = W^T for wave w (cols w*32..+31) from fp16 col-major Wt ----
__device__ inline void hoist_afrag_f16(const _Float16* __restrict__ Wt, int w, int l16, int lq,
                                       h8 afrag[2][4]) {
#pragma unroll
    for (int ct = 0; ct < 2; ++ct) {
        int c = w * 32 + ct * 16 + l16;
#pragma unroll
        for (int kb = 0; kb < 4; ++kb)
            afrag[ct][kb] = *(const h8*)(Wt + (size_t)c * DHID + kb * 32 + lq * 8);
    }
}

// ---- transpose body: Wt[c][k] = fp16(W[k][c]) (256 threads, 1 block) ----
__device__ inline void wtrans_body(const float* __restrict__ W, _Float16* __restrict__ Wt) {
    int t = threadIdx.x;
    int c = t & 127, k0 = (t >> 7) * 64;
#pragma unroll
    for (int kb = 0; kb < 8; ++kb) {
        h8 v;
#pragma unroll
        for (int j = 0; j < 8; ++j)
            v[j] = (_Float16)W[(size_t)(k0 + kb * 8 + j) * DHID + c];
        *(h8*)(Wt + (size_t)c * DHID + k0 + kb * 8) = v;
    }
}

// ---- partition body: bucket edges by dst>>9; packed entry (dst&511)<<17 | src ----
__device__ inline void partition_body(char* smem, const int* __restrict__ ei, int E, int nbuck,
                                      int* __restrict__ bcur, unsigned* __restrict__ packed, int blk) {
    unsigned* sdata = (unsigned*)smem;          // 16384 B
    int* lcnt  = (int*)(smem + 16384);
    int* lbase = (int*)(smem + 17408);
    int* loff  = (int*)(smem + 18432);
    int* lcur  = (int*)(smem + 19456);
    int* sscan = (int*)(smem + 20480);
    int t = threadIdx.x;
    int e0 = blk * PCHUNK;
    lcnt[t] = 0;
    __syncthreads();

    int sreg[16], dreg[16];
#pragma unroll
    for (int k = 0; k < 16; ++k) {
        int e = e0 + t + k * 256;
        if (e < E) { sreg[k] = ei[e]; dreg[k] = ei[E + e]; }
        else dreg[k] = -1;
    }

#pragma unroll
    for (int k = 0; k < 16; ++k)
        if (dreg[k] >= 0) atomicAdd(&lcnt[dreg[k] >> 9], 1);
    __syncthreads();

    int c = lcnt[t];
    sscan[t] = c;
    __syncthreads();
    for (int off = 1; off < 256; off <<= 1) {
        int v = (t >= off) ? sscan[t - off] : 0;
        __syncthreads();
        sscan[t] += v;
        __syncthreads();
    }
    loff[t] = sscan[t] - c;
    if (t < nbuck && c > 0) lbase[t] = atomicAdd(&bcur[t], c);
    lcur[t] = sscan[t] - c;
    __syncthreads();

#pragma unroll
    for (int k = 0; k < 16; ++k) {
        if (dreg[k] >= 0) {
            int b = dreg[k] >> 9;
            int pos = atomicAdd(&lcur[b], 1);
            sdata[pos] = ((unsigned)(dreg[k] & 511) << 17) | (unsigned)sreg[k];
        }
    }
    __syncthreads();

    int wid = t >> 6, lane = t & 63;
    for (int b = wid; b < nbuck; b += 4) {
        int cb = lcnt[b];
        if (cb == 0) continue;
        int gbase = b * BCAP + lbase[b];
        int sbase = loff[b];
        for (int k = lane; k < cb; k += 64) packed[gbase + k] = sdata[sbase + k];
    }
}

// ---- K0: edge partition (blocks < nPart) ∥ W1/W2 fp16 transposes (2 tail blocks) ----
__global__ __launch_bounds__(256) void k_part(const int* __restrict__ ei, int E, int nbuck,
                                              int* __restrict__ bcur, unsigned* __restrict__ packed,
                                              const float* __restrict__ W1, const float* __restrict__ W2,
                                              _Float16* __restrict__ W1t, _Float16* __restrict__ W2t,
                                              int nPart) {
    __shared__ __align__(16) char smem[SMEM_PART];
    int b = blockIdx.x;
    if (b < nPart)            partition_body(smem, ei, E, nbuck, bcur, packed, b);
    else if (b == nPart)      wtrans_body(W1, W1t);
    else                      wtrans_body(W2, W2t);
}

// ---- p2b body: per-bucket counting sort -> row_ptr, dinv, csr ----
__device__ inline void p2b_body(char* smem, const unsigned* __restrict__ packed,
                                const int* __restrict__ bcur,
                                int* __restrict__ row_ptr, float* __restrict__ dinv,
                                int* __restrict__ csr, int nbuck, int N, int E, int b) {
    int* c512   = (int*)smem;             // 2048 B
    int* cur512 = (int*)(smem + 2048);    // 2048 B
    int* sscan  = (int*)(smem + 4096);    // 1024 B
    int* sbk    = (int*)(smem + 5120);    // 1024 B
    int t = threadIdx.x;
    sbk[t] = (t < nbuck) ? bcur[t] : 0;
    c512[t] = 0; c512[t + 256] = 0;
    __syncthreads();
    for (int off = 1; off < 256; off <<= 1) {   // inclusive scan of bucket totals
        int v = (t >= off) ? sbk[t - off] : 0;
        __syncthreads();
        sbk[t] += v;
        __syncthreads();
    }
    int rbase = (b > 0) ? sbk[b - 1] : 0;
    int m = bcur[b];
    const unsigned* pb = packed + (size_t)b * BCAP;
    for (int i = t; i < m; i += 256) atomicAdd(&c512[pb[i] >> 17], 1);
    __syncthreads();
    int v0 = c512[2 * t], v1 = c512[2 * t + 1];
    int ps = v0 + v1;
    sscan[t] = ps;
    __syncthreads();
    for (int off = 1; off < 256; off <<= 1) {
        int v = (t >= off) ? sscan[t - off] : 0;
        __syncthreads();
        sscan[t] += v;
        __syncthreads();
    }
    int excl = sscan[t] - ps;
    cur512[2 * t] = excl;
    cur512[2 * t + 1] = excl + v0;

    int n0 = (b << 9) + 2 * t;
    if (n0 < N) {
        row_ptr[n0] = rbase + excl;
        dinv[n0] = rsqrtf((float)(v0 + 1));     // +1 self-loop
    }
    if (n0 + 1 < N) {
        row_ptr[n0 + 1] = rbase + excl + v0;
        dinv[n0 + 1] = rsqrtf((float)(v1 + 1));
    }
    if (b == 0 && t == 0) row_ptr[N] = E;
    __syncthreads();

    for (int i = t; i < m; i += 256) {
        unsigned p = pb[i];
        int dl = p >> 17;
        int src = (int)(p & 0x1FFFFu);
        int pos = atomicAdd(&cur512[dl], 1);
        csr[rbase + pos] = src;
    }
}

// ---- gemm1 body: Th[N,128] = fp16(X @ W1), UNSCALED (dinv applied in agg) ----
__device__ inline void gemm1_body(char* smem, const float* __restrict__ X,
                                  const _Float16* __restrict__ W1t,
                                  _Float16* __restrict__ Th, int N, int blk) {
    _Float16* Xs = (_Float16*)smem;
    int t = threadIdx.x;
    int w = t >> 6, l = t & 63, l16 = l & 15, lq = l >> 4;

    h8 afrag[2][4];
    hoist_afrag_f16(W1t, w, l16, lq, afrag);

    int rs = t >> 2, cs = (t & 3) * 32;
    int r0 = blk * 64;
    {
        int rg = r0 + rs; if (rg > N - 1) rg = N - 1;
        _Float16* sp = Xs + rs * XS_LD + cs;
        const float* xp = X + (size_t)rg * DHID + cs;
#pragma unroll
        for (int k = 0; k < 4; ++k) {
            float4 a = *(const float4*)(xp + k * 8);
            float4 b = *(const float4*)(xp + k * 8 + 4);
            h8 v;
            v[0] = (_Float16)a.x; v[1] = (_Float16)a.y;
            v[2] = (_Float16)a.z; v[3] = (_Float16)a.w;
            v[4] = (_Float16)b.x; v[5] = (_Float16)b.y;
            v[6] = (_Float16)b.z; v[7] = (_Float16)b.w;
            *(h8*)(sp + k * 8) = v;
        }
    }
    __syncthreads();

    f32x4 acc[4][2];
#pragma unroll
    for (int rt = 0; rt < 4; ++rt)
#pragma unroll
        for (int ct = 0; ct < 2; ++ct) acc[rt][ct] = (f32x4){0.f, 0.f, 0.f, 0.f};

#pragma unroll
    for (int rt = 0; rt < 4; ++rt) {
        const _Float16* bp = Xs + (rt * 16 + l16) * XS_LD + lq * 8;
#pragma unroll
        for (int kb = 0; kb < 4; ++kb) {
            h8 b = *(const h8*)(bp + kb * 32);
            acc[rt][0] = __builtin_amdgcn_mfma_f32_16x16x32_f16(afrag[0][kb], b, acc[rt][0], 0, 0, 0);
            acc[rt][1] = __builtin_amdgcn_mfma_f32_16x16x32_f16(afrag[1][kb], b, acc[rt][1], 0, 0, 0);
        }
    }

#pragma unroll
    for (int rt = 0; rt < 4; ++rt) {
        int r = r0 + rt * 16 + l16;
        if (r < N) {
#pragma unroll
            for (int ct = 0; ct < 2; ++ct) {
                h4 v;
#pragma unroll
                for (int j = 0; j < 4; ++j) v[j] = (_Float16)acc[rt][ct][j];
                *(h4*)(Th + (size_t)r * DHID + w * 32 + ct * 16 + lq * 4) = v;
            }
        }
    }
}

// ---- K1: p2b (blocks < nbuck, dispatched first) ∥ gemm1 (rest) — independent ----
__global__ __launch_bounds__(256) void k_mid(const unsigned* __restrict__ packed,
                                             const int* __restrict__ bcur,
                                             int* __restrict__ row_ptr, float* __restrict__ dinv,
                                             int* __restrict__ csr, int nbuck, int N, int E,
                                             const float* __restrict__ X,
                                             const _Float16* __restrict__ W1t,
                                             _Float16* __restrict__ Th) {
    __shared__ __align__(16) char smem[SMEM_MID];
    int b = blockIdx.x;
    if (b < nbuck)
        p2b_body(smem, packed, bcur, row_ptr, dinv, csr, nbuck, N, E, b);
    else
        gemm1_body(smem, X, W1t, Th, N, b - nbuck);
}

// ---- K2: agg layer-1 -> H fp16.  Pure gather, NO barrier (R10 lesson). ----
__global__ __launch_bounds__(256) void k_agg_mid(const _Float16* __restrict__ Th,
                                                 const int* __restrict__ row_ptr,
                                                 const int* __restrict__ csr,
                                                 const float* __restrict__ dinv,
                                                 const float* __restrict__ bias,
                                                 _Float16* __restrict__ H, int N) {
    int node = blockIdx.x * 16 + (threadIdx.x >> 4);
    int sl = threadIdx.x & 15;
    if (node >= N) return;

    int e = row_ptr[node];
    int end = row_ptr[node + 1];
    const h8* Tl = (const h8*)Th + sl;

    float acc[8];
#pragma unroll
    for (int c = 0; c < 8; ++c) acc[c] = 0.f;

    for (; e + 4 <= end; e += 4) {
        int s0 = csr[e], s1 = csr[e + 1], s2 = csr[e + 2], s3 = csr[e + 3];
        float d0 = dinv[s0], d1 = dinv[s1], d2 = dinv[s2], d3 = dinv[s3];
        h8 v0 = Tl[(size_t)s0 * 16];
        h8 v1 = Tl[(size_t)s1 * 16];
        h8 v2 = Tl[(size_t)s2 * 16];
        h8 v3 = Tl[(size_t)s3 * 16];
#pragma unroll
        for (int c = 0; c < 8; ++c) {
            float a0 = fmaf(d0, (float)v0[c], fmaf(d1, (float)v1[c], 0.f));
            float a1 = fmaf(d2, (float)v2[c], fmaf(d3, (float)v3[c], 0.f));
            acc[c] += a0 + a1;
        }
    }
    for (; e < end; ++e) {
        int s0 = csr[e];
        float d0 = dinv[s0];
        h8 va = Tl[(size_t)s0 * 16];
#pragma unroll
        for (int c = 0; c < 8; ++c) acc[c] = fmaf(d0, (float)va[c], acc[c]);
    }

    float dn = dinv[node];
    {   // self-loop
        h8 tv = Tl[(size_t)node * 16];
#pragma unroll
        for (int c = 0; c < 8; ++c) acc[c] = fmaf(dn, (float)tv[c], acc[c]);
    }

    const float* bp = bias + sl * 8;
    float4 b0 = *(const float4*)bp;
    float4 b1 = *(const float4*)(bp + 4);
    h8 hv;
    hv[0] = (_Float16)fmaxf(fmaf(dn, acc[0], b0.x), 0.f);
    hv[1] = (_Float16)fmaxf(fmaf(dn, acc[1], b0.y), 0.f);
    hv[2] = (_Float16)fmaxf(fmaf(dn, acc[2], b0.z), 0.f);
    hv[3] = (_Float16)fmaxf(fmaf(dn, acc[3], b0.w), 0.f);
    hv[4] = (_Float16)fmaxf(fmaf(dn, acc[4], b1.x), 0.f);
    hv[5] = (_Float16)fmaxf(fmaf(dn, acc[5], b1.y), 0.f);
    hv[6] = (_Float16)fmaxf(fmaf(dn, acc[6], b1.z), 0.f);
    hv[7] = (_Float16)fmaxf(fmaf(dn, acc[7], b1.w), 0.f);
    *(h8*)(H + (size_t)node * DHID + sl * 8) = hv;
}

// ---- K3: final agg gathers H directly, then per-wave fused GEMV:
//  S(H@W2) = (S·H)@W2 (aggregation is linear).  g = dinv_n·agg(H) -> fp16;
//  out = relu(g@W2 + b2)·Wl + bl via 32 MFMAs/wave (B-cols 0..3 valid) with
//  bpermute-assembled B-frags.  W2t staged in LDS ONCE + single barrier BEFORE
//  the gather (no gather coupling — R10 lesson).
__global__ __launch_bounds__(256) void k_agg_fin(const _Float16* __restrict__ H,
                                                 const int* __restrict__ row_ptr,
                                                 const int* __restrict__ csr,
                                                 const float* __restrict__ dinv,
                                                 const float* __restrict__ b2,
                                                 const _Float16* __restrict__ W2t,
                                                 const float* __restrict__ Wl,
                                                 const float* __restrict__ bl,
                                                 float* __restrict__ out, int N) {
    __shared__ _Float16 W2s[DHID * W2_LD];
    int t = threadIdx.x;
    {   // stage W2t [c][k] -> LDS stride W2_LD (4-way-max bank spread)
        int r = t >> 1, hh = (t & 1) * 64;
        const _Float16* src = W2t + (size_t)r * DHID + hh;
        _Float16* dst = W2s + r * W2_LD + hh;
#pragma unroll
        for (int k = 0; k < 8; ++k)
            *(h8*)(dst + k * 8) = *(const h8*)(src + k * 8);
    }
    __syncthreads();   // only barrier; before any divergent gather work

    int node = blockIdx.x * 16 + (t >> 4);
    int sl = t & 15;
    bool gvalid = node < N;
    int nc = gvalid ? node : N - 1;
    int e = row_ptr[nc];
    int end = row_ptr[nc + 1];
    if (!gvalid) end = e;
    const h8* Tl = (const h8*)H + sl;

    float acc[8];
#pragma unroll
    for (int c = 0; c < 8; ++c) acc[c] = 0.f;

    for (; e + 4 <= end; e += 4) {
        int s0 = csr[e], s1 = csr[e + 1], s2 = csr[e + 2], s3 = csr[e + 3];
        float d0 = dinv[s0], d1 = dinv[s1], d2 = dinv[s2], d3 = dinv[s3];
        h8 v0 = Tl[(size_t)s0 * 16];
        h8 v1 = Tl[(size_t)s1 * 16];
        h8 v2 = Tl[(size_t)s2 * 16];
        h8 v3 = Tl[(size_t)s3 * 16];
#pragma unroll
        for (int c = 0; c < 8; ++c) {
            float a0 = fmaf(d0, (float)v0[c], fmaf(d1, (float)v1[c], 0.f));
            float a1 = fmaf(d2, (float)v2[c], fmaf(d3, (float)v3[c], 0.f));
            acc[c] += a0 + a1;
        }
    }
    for (; e < end; ++e) {
        int s0 = csr[e];
        float d0 = dinv[s0];
        h8 va = Tl[(size_t)s0 * 16];
#pragma unroll
        for (int c = 0; c < 8; ++c) acc[c] = fmaf(d0, (float)va[c], acc[c]);
    }

    float dn = gvalid ? dinv[nc] : 0.f;
    {   // self-loop (clamped nc — safe load; dn=0 nulls it when invalid)
        h8 tv = Tl[(size_t)nc * 16];
#pragma unroll
        for (int c = 0; c < 8; ++c) acc[c] = fmaf(dn, (float)tv[c], acc[c]);
    }

    // g = dinv_n * agg  (fp16; scale-before-round, commutes with W2)
    h8 gv;
#pragma unroll
    for (int c = 0; c < 8; ++c) gv[c] = (_Float16)(dn * acc[c]);

    // ---- per-wave GEMV: D = W2^T g^T via 16x16x32 MFMA, B-cols 0..3 valid ----
    int l = t & 63;            // wave-local lane
    int n = l & 15;            // B-col = wave-local node (valid < 4)
    int lq = l >> 4;           // 0..3
    i32x4 gi = *(i32x4*)&gv;
    h8 bfrag[4];
    int lbase = (n * 16 + lq) * 4;     // src lane = n*16 + kb*4 + lq (bytes)
#pragma unroll
    for (int kb = 0; kb < 4; ++kb) {
        int idx = lbase + kb * 16;
        i32x4 bi;
        bi[0] = __builtin_amdgcn_ds_bpermute(idx, gi[0]);
        bi[1] = __builtin_amdgcn_ds_bpermute(idx, gi[1]);
        bi[2] = __builtin_amdgcn_ds_bpermute(idx, gi[2]);
        bi[3] = __builtin_amdgcn_ds_bpermute(idx, gi[3]);
        bfrag[kb] = *(h8*)&bi;
    }

    float p = 0.f;
#pragma unroll
    for (int ct = 0; ct < 8; ++ct) {
        f32x4 d4 = {0.f, 0.f, 0.f, 0.f};
        const _Float16* ap = W2s + (ct * 16 + n) * W2_LD + lq * 8;
#pragma unroll
        for (int kb = 0; kb < 4; ++kb) {
            h8 a = *(const h8*)(ap + kb * 32);
            d4 = __builtin_amdgcn_mfma_f32_16x16x32_f16(a, bfrag[kb], d4, 0, 0, 0);
        }
        // output dims: ct*16 + lq*4 + reg
        float4 bb = *(const float4*)(b2 + ct * 16 + lq * 4);
        float4 wl = *(const float4*)(Wl + ct * 16 + lq * 4);
        p += fmaxf(d4[0] + bb.x, 0.f) * wl.x + fmaxf(d4[1] + bb.y, 0.f) * wl.y +
             fmaxf(d4[2] + bb.z, 0.f) * wl.z + fmaxf(d4[3] + bb.w, 0.f) * wl.w;
    }
    p += __shfl_xor(p, 16, 64);
    p += __shfl_xor(p, 32, 64);

    if (lq == 0 && n < 4) {
        int w = t >> 6;
        int gnode = blockIdx.x * 16 + w * 4 + n;
        if (gnode < N) out[gnode] = p + bl[0];
    }
}

// ---------------- launch ----------------
extern "C" void kernel_launch(void* const* d_in, const int* in_sizes, int n_in,
                              void* d_out, int out_size, void* d_ws, size_t ws_size,
                              hipStream_t stream) {
    const float* x  = (const float*)d_in[0];
    const int*   ei = (const int*)d_in[1];
    const float* W1 = (const float*)d_in[2];
    const float* b1 = (const float*)d_in[3];
    const float* W2 = (const float*)d_in[4];
    const float* b2 = (const float*)d_in[5];
    const float* Wl = (const float*)d_in[6];
    const float* bl = (const float*)d_in[7];
    float* out = (float*)d_out;

    int N = in_sizes[0] / DHID;     // 100000
    int E = in_sizes[1] / 2;        // 1600000
    int nbuck = (N + 511) / 512;    // 196
    int nRB = (N + 63) / 64;        // 1563
    int nPart = (E + PCHUNK - 1) / PCHUNK;  // 391

    char* ws = (char*)d_ws;
    size_t off = 0;
    auto alloc = [&](size_t bytes) -> void* {
        void* p = ws + off;
        off += (bytes + 255) & ~(size_t)255;
        return p;
    };
    float*    dinv     = (float*)alloc((size_t)N * 4);
    int*      row_ptr  = (int*)alloc((size_t)(N + 1) * 4);
    int*      bcur     = (int*)alloc((size_t)nbuck * 4);
    int*      csr      = (int*)alloc((size_t)E * 4);
    unsigned* packed   = (unsigned*)alloc((size_t)nbuck * BCAP * 4);
    _Float16* Th       = (_Float16*)alloc((size_t)N * DHID * 2);
    _Float16* H        = (_Float16*)alloc((size_t)N * DHID * 2);
    _Float16* W1t      = (_Float16*)alloc((size_t)DHID * DHID * 2);
    _Float16* W2t      = (_Float16*)alloc((size_t)DHID * DHID * 2);

    (void)hipMemsetAsync(bcur, 0, (size_t)nbuck * 4, stream);

    // K0: edge partition ∥ W1/W2 fp16 transposes
    k_part<<<nPart + 2, 256, 0, stream>>>(ei, E, nbuck, bcur, packed, W1, W2, W1t, W2t, nPart);
    // K1: p2b (first 196 blocks) ∥ gemm1 (rest)
    k_mid<<<nbuck + nRB, 256, 0, stream>>>(packed, bcur, row_ptr, dinv, csr, nbuck, N, E,
                                           x, W1t, Th);
    // K2: agg layer-1 -> H (pure gather, no barrier)
    k_agg_mid<<<(N + 15) / 16, 256, 0, stream>>>(Th, row_ptr, csr, dinv, b1, H, N);
    // K3: final agg over H + fused per-wave W2 GEMV + Wl projection
    k_agg_fin<<<(N + 15) / 16, 256, 0, stream>>>(H, row_ptr, csr, dinv, b2, W2t, Wl, bl, out, N);
}

// Round 14
// 200.682 us; speedup vs baseline: 1.3713x; 1.3713x over previous
//
#include <hip/hip_runtime.h>

#define DHID 128
#define BCAP 10240         // per-bucket capacity (mean 8163, 23 sigma)
#define PCHUNK 4096        // edges per partition block
#define XS_LD 136          // LDS row stride in fp16 elems (128 + 8 pad)
#define SMEM_PART 21504    // partition smem bytes
#define SMEM_MID  17408    // gemm1 tile 64*136*2 (> p2b's 6144)

typedef _Float16 h4 __attribute__((ext_vector_type(4)));
typedef _Float16 h8 __attribute__((ext_vector_type(8)));
typedef float    f32x4 __attribute__((ext_vector_type(4)));

// ---- hoist A-frags = W^T for wave w (cols w*32..+31) from fp16 col-major Wt ----
__device__ inline void hoist_afrag_f16(const _Float16* __restrict__ Wt, int w, int l16, int lq,
                                       h8 afrag[2][4]) {
#pragma unroll
    for (int ct = 0; ct < 2; ++ct) {
        int c = w * 32 + ct * 16 + l16;
#pragma unroll
        for (int kb = 0; kb < 4; ++kb)
            afrag[ct][kb] = *(const h8*)(Wt + (size_t)c * DHID + kb * 32 + lq * 8);
    }
}

// ---- transpose body: Wt[c][k] = fp16(W[k][c]) (256 threads, 1 block) ----
__device__ inline void wtrans_body(const float* __restrict__ W, _Float16* __restrict__ Wt) {
    int t = threadIdx.x;
    int c = t & 127, k0 = (t >> 7) * 64;
#pragma unroll
    for (int kb = 0; kb < 8; ++kb) {
        h8 v;
#pragma unroll
        for (int j = 0; j < 8; ++j)
            v[j] = (_Float16)W[(size_t)(k0 + kb * 8 + j) * DHID + c];
        *(h8*)(Wt + (size_t)c * DHID + k0 + kb * 8) = v;
    }
}

// ---- partition body: bucket edges by dst>>9; packed entry (dst&511)<<17 | src ----
__device__ inline void partition_body(char* smem, const int* __restrict__ ei, int E, int nbuck,
                                      int* __restrict__ bcur, unsigned* __restrict__ packed, int blk) {
    unsigned* sdata = (unsigned*)smem;          // 16384 B
    int* lcnt  = (int*)(smem + 16384);
    int* lbase = (int*)(smem + 17408);
    int* loff  = (int*)(smem + 18432);
    int* lcur  = (int*)(smem + 19456);
    int* sscan = (int*)(smem + 20480);
    int t = threadIdx.x;
    int e0 = blk * PCHUNK;
    lcnt[t] = 0;
    __syncthreads();

    int sreg[16], dreg[16];
#pragma unroll
    for (int k = 0; k < 16; ++k) {
        int e = e0 + t + k * 256;
        if (e < E) { sreg[k] = ei[e]; dreg[k] = ei[E + e]; }
        else dreg[k] = -1;
    }

#pragma unroll
    for (int k = 0; k < 16; ++k)
        if (dreg[k] >= 0) atomicAdd(&lcnt[dreg[k] >> 9], 1);
    __syncthreads();

    int c = lcnt[t];
    sscan[t] = c;
    __syncthreads();
    for (int off = 1; off < 256; off <<= 1) {
        int v = (t >= off) ? sscan[t - off] : 0;
        __syncthreads();
        sscan[t] += v;
        __syncthreads();
    }
    loff[t] = sscan[t] - c;
    if (t < nbuck && c > 0) lbase[t] = atomicAdd(&bcur[t], c);
    lcur[t] = sscan[t] - c;
    __syncthreads();

#pragma unroll
    for (int k = 0; k < 16; ++k) {
        if (dreg[k] >= 0) {
            int b = dreg[k] >> 9;
            int pos = atomicAdd(&lcur[b], 1);
            sdata[pos] = ((unsigned)(dreg[k] & 511) << 17) | (unsigned)sreg[k];
        }
    }
    __syncthreads();

    int wid = t >> 6, lane = t & 63;
    for (int b = wid; b < nbuck; b += 4) {
        int cb = lcnt[b];
        if (cb == 0) continue;
        int gbase = b * BCAP + lbase[b];
        int sbase = loff[b];
        for (int k = lane; k < cb; k += 64) packed[gbase + k] = sdata[sbase + k];
    }
}

// ---- K0: edge partition (blocks < nPart) ∥ W1/W2 fp16 transposes (2 tail blocks) ----
__global__ __launch_bounds__(256) void k_part(const int* __restrict__ ei, int E, int nbuck,
                                              int* __restrict__ bcur, unsigned* __restrict__ packed,
                                              const float* __restrict__ W1, const float* __restrict__ W2,
                                              _Float16* __restrict__ W1t, _Float16* __restrict__ W2t,
                                              int nPart) {
    __shared__ __align__(16) char smem[SMEM_PART];
    int b = blockIdx.x;
    if (b < nPart)            partition_body(smem, ei, E, nbuck, bcur, packed, b);
    else if (b == nPart)      wtrans_body(W1, W1t);
    else                      wtrans_body(W2, W2t);
}

// ---- p2b body: per-bucket counting sort -> row_ptr, dinv, csr ----
__device__ inline void p2b_body(char* smem, const unsigned* __restrict__ packed,
                                const int* __restrict__ bcur,
                                int* __restrict__ row_ptr, float* __restrict__ dinv,
                                int* __restrict__ csr, int nbuck, int N, int E, int b) {
    int* c512   = (int*)smem;             // 2048 B
    int* cur512 = (int*)(smem + 2048);    // 2048 B
    int* sscan  = (int*)(smem + 4096);    // 1024 B
    int* sbk    = (int*)(smem + 5120);    // 1024 B
    int t = threadIdx.x;
    sbk[t] = (t < nbuck) ? bcur[t] : 0;
    c512[t] = 0; c512[t + 256] = 0;
    __syncthreads();
    for (int off = 1; off < 256; off <<= 1) {   // inclusive scan of bucket totals
        int v = (t >= off) ? sbk[t - off] : 0;
        __syncthreads();
        sbk[t] += v;
        __syncthreads();
    }
    int rbase = (b > 0) ? sbk[b - 1] : 0;
    int m = bcur[b];
    const unsigned* pb = packed + (size_t)b * BCAP;
    for (int i = t; i < m; i += 256) atomicAdd(&c512[pb[i] >> 17], 1);
    __syncthreads();
    int v0 = c512[2 * t], v1 = c512[2 * t + 1];
    int ps = v0 + v1;
    sscan[t] = ps;
    __syncthreads();
    for (int off = 1; off < 256; off <<= 1) {
        int v = (t >= off) ? sscan[t - off] : 0;
        __syncthreads();
        sscan[t] += v;
        __syncthreads();
    }
    int excl = sscan[t] - ps;
    cur512[2 * t] = excl;
    cur512[2 * t + 1] = excl + v0;

    int n0 = (b << 9) + 2 * t;
    if (n0 < N) {
        row_ptr[n0] = rbase + excl;
        dinv[n0] = rsqrtf((float)(v0 + 1));     // +1 self-loop
    }
    if (n0 + 1 < N) {
        row_ptr[n0 + 1] = rbase + excl + v0;
        dinv[n0 + 1] = rsqrtf((float)(v1 + 1));
    }
    if (b == 0 && t == 0) row_ptr[N] = E;
    __syncthreads();

    for (int i = t; i < m; i += 256) {
        unsigned p = pb[i];
        int dl = p >> 17;
        int src = (int)(p & 0x1FFFFu);
        int pos = atomicAdd(&cur512[dl], 1);
        csr[rbase + pos] = src;
    }
}

// ---- gemm1 body: Th[N,128] = fp16(X @ W1), UNSCALED (dinv applied in agg) ----
__device__ inline void gemm1_body(char* smem, const float* __restrict__ X,
                                  const _Float16* __restrict__ W1t,
                                  _Float16* __restrict__ Th, int N, int blk) {
    _Float16* Xs = (_Float16*)smem;
    int t = threadIdx.x;
    int w = t >> 6, l = t & 63, l16 = l & 15, lq = l >> 4;

    h8 afrag[2][4];
    hoist_afrag_f16(W1t, w, l16, lq, afrag);

    int rs = t >> 2, cs = (t & 3) * 32;
    int r0 = blk * 64;
    {
        int rg = r0 + rs; if (rg > N - 1) rg = N - 1;
        _Float16* sp = Xs + rs * XS_LD + cs;
        const float* xp = X + (size_t)rg * DHID + cs;
#pragma unroll
        for (int k = 0; k < 4; ++k) {
            float4 a = *(const float4*)(xp + k * 8);
            float4 b = *(const float4*)(xp + k * 8 + 4);
            h8 v;
            v[0] = (_Float16)a.x; v[1] = (_Float16)a.y;
            v[2] = (_Float16)a.z; v[3] = (_Float16)a.w;
            v[4] = (_Float16)b.x; v[5] = (_Float16)b.y;
            v[6] = (_Float16)b.z; v[7] = (_Float16)b.w;
            *(h8*)(sp + k * 8) = v;
        }
    }
    __syncthreads();

    f32x4 acc[4][2];
#pragma unroll
    for (int rt = 0; rt < 4; ++rt)
#pragma unroll
        for (int ct = 0; ct < 2; ++ct) acc[rt][ct] = (f32x4){0.f, 0.f, 0.f, 0.f};

#pragma unroll
    for (int rt = 0; rt < 4; ++rt) {
        const _Float16* bp = Xs + (rt * 16 + l16) * XS_LD + lq * 8;
#pragma unroll
        for (int kb = 0; kb < 4; ++kb) {
            h8 b = *(const h8*)(bp + kb * 32);
            acc[rt][0] = __builtin_amdgcn_mfma_f32_16x16x32_f16(afrag[0][kb], b, acc[rt][0], 0, 0, 0);
            acc[rt][1] = __builtin_amdgcn_mfma_f32_16x16x32_f16(afrag[1][kb], b, acc[rt][1], 0, 0, 0);
        }
    }

#pragma unroll
    for (int rt = 0; rt < 4; ++rt) {
        int r = r0 + rt * 16 + l16;
        if (r < N) {
#pragma unroll
            for (int ct = 0; ct < 2; ++ct) {
                h4 v;
#pragma unroll
                for (int j = 0; j < 4; ++j) v[j] = (_Float16)acc[rt][ct][j];
                *(h4*)(Th + (size_t)r * DHID + w * 32 + ct * 16 + lq * 4) = v;
            }
        }
    }
}

// ---- K1: p2b (blocks < nbuck, dispatched first) ∥ gemm1 (rest) — independent ----
__global__ __launch_bounds__(256) void k_mid(const unsigned* __restrict__ packed,
                                             const int* __restrict__ bcur,
                                             int* __restrict__ row_ptr, float* __restrict__ dinv,
                                             int* __restrict__ csr, int nbuck, int N, int E,
                                             const float* __restrict__ X,
                                             const _Float16* __restrict__ W1t,
                                             _Float16* __restrict__ Th) {
    __shared__ __align__(16) char smem[SMEM_MID];
    int b = blockIdx.x;
    if (b < nbuck)
        p2b_body(smem, packed, bcur, row_ptr, dinv, csr, nbuck, N, E, b);
    else
        gemm1_body(smem, X, W1t, Th, N, b - nbuck);
}

// ---- K2: agg layer-1 -> H fp16.  Pure gather: NO barrier, 0 LDS, 32 VGPR
//      (R13 lesson: gather throughput is concurrency-bound — keep occupancy max). ----
__global__ __launch_bounds__(256) void k_agg_mid(const _Float16* __restrict__ Th,
                                                 const int* __restrict__ row_ptr,
                                                 const int* __restrict__ csr,
                                                 const float* __restrict__ dinv,
                                                 const float* __restrict__ bias,
                                                 _Float16* __restrict__ H, int N) {
    int node = blockIdx.x * 16 + (threadIdx.x >> 4);
    int sl = threadIdx.x & 15;
    if (node >= N) return;

    int e = row_ptr[node];
    int end = row_ptr[node + 1];
    const h8* Tl = (const h8*)Th + sl;

    float acc[8];
#pragma unroll
    for (int c = 0; c < 8; ++c) acc[c] = 0.f;

    for (; e + 4 <= end; e += 4) {
        int s0 = csr[e], s1 = csr[e + 1], s2 = csr[e + 2], s3 = csr[e + 3];
        float d0 = dinv[s0], d1 = dinv[s1], d2 = dinv[s2], d3 = dinv[s3];
        h8 v0 = Tl[(size_t)s0 * 16];
        h8 v1 = Tl[(size_t)s1 * 16];
        h8 v2 = Tl[(size_t)s2 * 16];
        h8 v3 = Tl[(size_t)s3 * 16];
#pragma unroll
        for (int c = 0; c < 8; ++c) {
            float a0 = fmaf(d0, (float)v0[c], fmaf(d1, (float)v1[c], 0.f));
            float a1 = fmaf(d2, (float)v2[c], fmaf(d3, (float)v3[c], 0.f));
            acc[c] += a0 + a1;
        }
    }
    for (; e < end; ++e) {
        int s0 = csr[e];
        float d0 = dinv[s0];
        h8 va = Tl[(size_t)s0 * 16];
#pragma unroll
        for (int c = 0; c < 8; ++c) acc[c] = fmaf(d0, (float)va[c], acc[c]);
    }

    float dn = dinv[node];
    {   // self-loop
        h8 tv = Tl[(size_t)node * 16];
#pragma unroll
        for (int c = 0; c < 8; ++c) acc[c] = fmaf(dn, (float)tv[c], acc[c]);
    }

    const float* bp = bias + sl * 8;
    float4 b0 = *(const float4*)bp;
    float4 b1 = *(const float4*)(bp + 4);
    h8 hv;
    hv[0] = (_Float16)fmaxf(fmaf(dn, acc[0], b0.x), 0.f);
    hv[1] = (_Float16)fmaxf(fmaf(dn, acc[1], b0.y), 0.f);
    hv[2] = (_Float16)fmaxf(fmaf(dn, acc[2], b0.z), 0.f);
    hv[3] = (_Float16)fmaxf(fmaf(dn, acc[3], b0.w), 0.f);
    hv[4] = (_Float16)fmaxf(fmaf(dn, acc[4], b1.x), 0.f);
    hv[5] = (_Float16)fmaxf(fmaf(dn, acc[5], b1.y), 0.f);
    hv[6] = (_Float16)fmaxf(fmaf(dn, acc[6], b1.z), 0.f);
    hv[7] = (_Float16)fmaxf(fmaf(dn, acc[7], b1.w), 0.f);
    *(h8*)(H + (size_t)node * DHID + sl * 8) = hv;
}

// ---- K3: gemm2: Th2[N,128] = fp16(H @ W2), unscaled.  fp16 in, LDS-staged.
//      Kept SEPARATE from the gathers (R13 lesson: dense work must not ride
//      along in a gather kernel — the LDS/VGPR context halves occupancy). ----
__global__ __launch_bounds__(256) void k_gemm_l2(const _Float16* __restrict__ H,
                                                 const _Float16* __restrict__ W2t,
                                                 _Float16* __restrict__ Th2, int N) {
    __shared__ _Float16 Xs[64 * XS_LD];
    int t = threadIdx.x;
    int w = t >> 6, l = t & 63, l16 = l & 15, lq = l >> 4;

    h8 afrag[2][4];
    hoist_afrag_f16(W2t, w, l16, lq, afrag);

    int rs = t >> 2, cs = (t & 3) * 32;
    int r0 = blockIdx.x * 64;
    {
        int rg = r0 + rs; if (rg > N - 1) rg = N - 1;
        _Float16* sp = Xs + rs * XS_LD + cs;
        const _Float16* xp = H + (size_t)rg * DHID + cs;
#pragma unroll
        for (int k = 0; k < 4; ++k)
            *(h8*)(sp + k * 8) = *(const h8*)(xp + k * 8);
    }
    __syncthreads();

    f32x4 acc[4][2];
#pragma unroll
    for (int rt = 0; rt < 4; ++rt)
#pragma unroll
        for (int ct = 0; ct < 2; ++ct) acc[rt][ct] = (f32x4){0.f, 0.f, 0.f, 0.f};

#pragma unroll
    for (int rt = 0; rt < 4; ++rt) {
        const _Float16* bp = Xs + (rt * 16 + l16) * XS_LD + lq * 8;
#pragma unroll
        for (int kb = 0; kb < 4; ++kb) {
            h8 b = *(const h8*)(bp + kb * 32);
            acc[rt][0] = __builtin_amdgcn_mfma_f32_16x16x32_f16(afrag[0][kb], b, acc[rt][0], 0, 0, 0);
            acc[rt][1] = __builtin_amdgcn_mfma_f32_16x16x32_f16(afrag[1][kb], b, acc[rt][1], 0, 0, 0);
        }
    }

#pragma unroll
    for (int rt = 0; rt < 4; ++rt) {
        int r = r0 + rt * 16 + l16;
        if (r < N) {
#pragma unroll
            for (int ct = 0; ct < 2; ++ct) {
                h4 v;
#pragma unroll
                for (int j = 0; j < 4; ++j) v[j] = (_Float16)acc[rt][ct][j];
                *(h4*)(Th2 + (size_t)r * DHID + w * 32 + ct * 16 + lq * 4) = v;
            }
        }
    }
}

// ---- K4: final agg + Wl projection.  Pure gather, minimal context. ----
__global__ __launch_bounds__(256) void k_agg_fin(const _Float16* __restrict__ Th2,
                                                 const int* __restrict__ row_ptr,
                                                 const int* __restrict__ csr,
                                                 const float* __restrict__ dinv,
                                                 const float* __restrict__ bias,
                                                 const float* __restrict__ Wl,
                                                 const float* __restrict__ bl,
                                                 float* __restrict__ out, int N) {
    int node = blockIdx.x * 16 + (threadIdx.x >> 4);
    int sl = threadIdx.x & 15;
    if (node >= N) return;

    int e = row_ptr[node];
    int end = row_ptr[node + 1];
    const h8* Tl = (const h8*)Th2 + sl;

    float acc[8];
#pragma unroll
    for (int c = 0; c < 8; ++c) acc[c] = 0.f;

    for (; e + 4 <= end; e += 4) {
        int s0 = csr[e], s1 = csr[e + 1], s2 = csr[e + 2], s3 = csr[e + 3];
        float d0 = dinv[s0], d1 = dinv[s1], d2 = dinv[s2], d3 = dinv[s3];
        h8 v0 = Tl[(size_t)s0 * 16];
        h8 v1 = Tl[(size_t)s1 * 16];
        h8 v2 = Tl[(size_t)s2 * 16];
        h8 v3 = Tl[(size_t)s3 * 16];
#pragma unroll
        for (int c = 0; c < 8; ++c) {
            float a0 = fmaf(d0, (float)v0[c], fmaf(d1, (float)v1[c], 0.f));
            float a1 = fmaf(d2, (float)v2[c], fmaf(d3, (float)v3[c], 0.f));
            acc[c] += a0 + a1;
        }
    }
    for (; e < end; ++e) {
        int s0 = csr[e];
        float d0 = dinv[s0];
        h8 va = Tl[(size_t)s0 * 16];
#pragma unroll
        for (int c = 0; c < 8; ++c) acc[c] = fmaf(d0, (float)va[c], acc[c]);
    }

    float dn = dinv[node];
    {   // self-loop
        h8 tv = Tl[(size_t)node * 16];
#pragma unroll
        for (int c = 0; c < 8; ++c) acc[c] = fmaf(dn, (float)tv[c], acc[c]);
    }

    const float* bp = bias + sl * 8;
    float4 b0 = *(const float4*)bp;
    float4 b1 = *(const float4*)(bp + 4);
    float r[8];
    r[0] = fmaxf(fmaf(dn, acc[0], b0.x), 0.f);
    r[1] = fmaxf(fmaf(dn, acc[1], b0.y), 0.f);
    r[2] = fmaxf(fmaf(dn, acc[2], b0.z), 0.f);
    r[3] = fmaxf(fmaf(dn, acc[3], b0.w), 0.f);
    r[4] = fmaxf(fmaf(dn, acc[4], b1.x), 0.f);
    r[5] = fmaxf(fmaf(dn, acc[5], b1.y), 0.f);
    r[6] = fmaxf(fmaf(dn, acc[6], b1.z), 0.f);
    r[7] = fmaxf(fmaf(dn, acc[7], b1.w), 0.f);

    const float* wp = Wl + sl * 8;
    float4 w0 = *(const float4*)wp;
    float4 w1 = *(const float4*)(wp + 4);
    float p = r[0] * w0.x + r[1] * w0.y + r[2] * w0.z + r[3] * w0.w +
              r[4] * w1.x + r[5] * w1.y + r[6] * w1.z + r[7] * w1.w;
#pragma unroll
    for (int off = 8; off > 0; off >>= 1) p += __shfl_down(p, off, 16);
    if (sl == 0) out[node] = p + bl[0];
}

// ---------------- launch ----------------
extern "C" void kernel_launch(void* const* d_in, const int* in_sizes, int n_in,
                              void* d_out, int out_size, void* d_ws, size_t ws_size,
                              hipStream_t stream) {
    const float* x  = (const float*)d_in[0];
    const int*   ei = (const int*)d_in[1];
    const float* W1 = (const float*)d_in[2];
    const float* b1 = (const float*)d_in[3];
    const float* W2 = (const float*)d_in[4];
    const float* b2 = (const float*)d_in[5];
    const float* Wl = (const float*)d_in[6];
    const float* bl = (const float*)d_in[7];
    float* out = (float*)d_out;

    int N = in_sizes[0] / DHID;     // 100000
    int E = in_sizes[1] / 2;        // 1600000
    int nbuck = (N + 511) / 512;    // 196
    int nRB = (N + 63) / 64;        // 1563
    int nPart = (E + PCHUNK - 1) / PCHUNK;  // 391

    char* ws = (char*)d_ws;
    size_t off = 0;
    auto alloc = [&](size_t bytes) -> void* {
        void* p = ws + off;
        off += (bytes + 255) & ~(size_t)255;
        return p;
    };
    float*    dinv     = (float*)alloc((size_t)N * 4);
    int*      row_ptr  = (int*)alloc((size_t)(N + 1) * 4);
    int*      bcur     = (int*)alloc((size_t)nbuck * 4);
    int*      csr      = (int*)alloc((size_t)E * 4);
    unsigned* packed   = (unsigned*)alloc((size_t)nbuck * BCAP * 4);
    _Float16* Th       = (_Float16*)alloc((size_t)N * DHID * 2);
    _Float16* Th2      = (_Float16*)alloc((size_t)N * DHID * 2);
    _Float16* H        = (_Float16*)alloc((size_t)N * DHID * 2);
    _Float16* W1t      = (_Float16*)alloc((size_t)DHID * DHID * 2);
    _Float16* W2t      = (_Float16*)alloc((size_t)DHID * DHID * 2);

    (void)hipMemsetAsync(bcur, 0, (size_t)nbuck * 4, stream);

    // K0: edge partition ∥ W1/W2 fp16 transposes
    k_part<<<nPart + 2, 256, 0, stream>>>(ei, E, nbuck, bcur, packed, W1, W2, W1t, W2t, nPart);
    // K1: p2b (first 196 blocks) ∥ gemm1 (rest)
    k_mid<<<nbuck + nRB, 256, 0, stream>>>(packed, bcur, row_ptr, dinv, csr, nbuck, N, E,
                                           x, W1t, Th);
    // K2: agg layer-1 -> H (pure gather, no barrier, minimal context)
    k_agg_mid<<<(N + 15) / 16, 256, 0, stream>>>(Th, row_ptr, csr, dinv, b1, H, N);
    // K3: gemm2 -> Th2 (dense, separate)
    k_gemm_l2<<<nRB, 256, 0, stream>>>(H, W2t, Th2, N);
    // K4: final agg + Wl projection (pure gather)
    k_agg_fin<<<(N + 15) / 16, 256, 0, stream>>>(Th2, row_ptr, csr, dinv, b2, Wl, bl, out, N);
}